// Round 4
// baseline (209.640 us; speedup 1.0000x reference)
//
#include <hip/hip_runtime.h>
#include <hip/hip_bf16.h>
#include <math.h>

typedef __hip_bfloat16 bf16;
using f32x4  = __attribute__((ext_vector_type(4))) float;
using f32x2  = __attribute__((ext_vector_type(2))) float;
using bf16x8 = __attribute__((ext_vector_type(8))) short;

constexpr int BS = 2, NQ = 22223, MROWS = 44446;
constexpr int LH[4] = {100, 50, 25, 13};
constexpr int LW[4] = {167, 84, 42, 21};
constexpr int LSTART[4] = {0, 16700, 20900, 21950};
// Padded levels: +1 left/top, +2 right/bottom  (Wp=W+3, Hp=H+3)
constexpr int PLW[4] = {170, 87, 45, 24};
constexpr int PLSTART[4] = {0, 17510, 22121, 23381};
constexpr int PTOT = 23765;          // padded pixels per batch image

constexpr int BM = 128, BN = 128, BK = 32;
constexpr int LDT = 40;  // LDS row stride (bf16): 80B, 16B-aligned, 2-way banks

// ---------------------------------------------------------------------------
__global__ __launch_bounds__(256) void prep_weights(
    const float* __restrict__ W_vp, const float* __restrict__ W_so,
    const float* __restrict__ W_aw, const float* __restrict__ W_op,
    const float* __restrict__ b_so, const float* __restrict__ b_aw,
    bf16* __restrict__ Wt_vp, bf16* __restrict__ Wt_cat,
    bf16* __restrict__ Wt_op, float* __restrict__ bcat)
{
    int i = blockIdx.x * 256 + threadIdx.x;
    if (i < 256 * 256) {
        int n = i >> 8, k = i & 255;
        Wt_vp[i] = __float2bfloat16(W_vp[k * 256 + n]);
        Wt_op[i] = __float2bfloat16(W_op[k * 256 + n]);
    }
    if (i < 384 * 256) {
        int n = i >> 8, k = i & 255;
        float v = (n < 256) ? W_so[k * 256 + n] : W_aw[k * 128 + (n - 256)];
        Wt_cat[i] = __float2bfloat16(v);
    }
    if (i < 384) bcat[i] = (i < 256) ? b_so[i] : b_aw[i - 256];
}

// Map flat value-row -> padded vproj pixel index (level-wise, +1,+1 offset)
__device__ inline int pad_row_idx(int r) {
    int b = 0, pix = r;
    if (pix >= NQ) { b = 1; pix -= NQ; }
    int base;
    if (pix < LSTART[1])      { int rel = pix;             int y = rel / 167; int x = rel - y * 167; base = PLSTART[0] + (y + 1) * 170 + (x + 1); }
    else if (pix < LSTART[2]) { int rel = pix - LSTART[1]; int y = rel / 84;  int x = rel - y * 84;  base = PLSTART[1] + (y + 1) * 87  + (x + 1); }
    else if (pix < LSTART[3]) { int rel = pix - LSTART[2]; int y = rel / 42;  int x = rel - y * 42;  base = PLSTART[2] + (y + 1) * 45  + (x + 1); }
    else                      { int rel = pix - LSTART[3]; int y = rel / 21;  int x = rel - y * 21;  base = PLSTART[3] + (y + 1) * 24  + (x + 1); }
    return b * PTOT + base;
}

// ---------------------------------------------------------------------------
// bf16 MFMA GEMM: out[M][N] = A[M][K=256] @ Wt[N][256]^T + bias (+resid).
// 128x128 tile, 4 waves, BK=32. PADMAP: scatter rows into padded vproj layout.
// ---------------------------------------------------------------------------
template<bool A_BF16, bool OUT_BF16, bool RESID, bool PADMAP>
__global__ __launch_bounds__(256) void gemm_mfma(
    const void* __restrict__ Av, int lda,
    const bf16* __restrict__ Wt,
    const float* __restrict__ bias,
    const float* __restrict__ resid,      // fp32, ld 256
    void* __restrict__ outv, int ldo, int M)
{
    __shared__ bf16 As[BM * LDT];
    __shared__ bf16 Bs[BN * LDT];

    const int tid = threadIdx.x;
    const int lane = tid & 63;
    const int wv = tid >> 6;
    const int wm = (wv >> 1) * 64, wn = (wv & 1) * 64;
    const int row0 = blockIdx.x * BM;
    const int bn0 = blockIdx.y * BN;
    const int l15 = lane & 15, l4 = lane >> 4;

    f32x4 acc[4][4];
#pragma unroll
    for (int m = 0; m < 4; ++m)
#pragma unroll
        for (int n = 0; n < 4; ++n) { acc[m][n][0]=0.f; acc[m][n][1]=0.f; acc[m][n][2]=0.f; acc[m][n][3]=0.f; }

    for (int k0 = 0; k0 < 256; k0 += BK) {
        __syncthreads();
#pragma unroll
        for (int t = 0; t < 2; ++t) {
            int idx = tid + t * 256;
            int r = idx >> 2, s = idx & 3;
            {
                int grow = row0 + r; if (grow >= M) grow = M - 1;
                bf16 tmp[8];
                if constexpr (A_BF16) {
                    const bf16* ap = (const bf16*)Av + (size_t)grow * lda + (k0 + s * 8);
                    *(uint4*)tmp = *(const uint4*)ap;
                } else {
                    const float* ap = (const float*)Av + (size_t)grow * lda + (k0 + s * 8);
                    f32x4 v0 = *(const f32x4*)ap;
                    f32x4 v1 = *(const f32x4*)(ap + 4);
#pragma unroll
                    for (int j = 0; j < 4; ++j) tmp[j] = __float2bfloat16(v0[j]);
#pragma unroll
                    for (int j = 0; j < 4; ++j) tmp[4 + j] = __float2bfloat16(v1[j]);
                }
                *(uint4*)&As[r * LDT + s * 8] = *(const uint4*)tmp;
            }
            {
                const bf16* bp = Wt + (size_t)(bn0 + r) * 256 + (k0 + s * 8);
                *(uint4*)&Bs[r * LDT + s * 8] = *(const uint4*)bp;
            }
        }
        __syncthreads();

        bf16x8 af[4], bfr[4];
#pragma unroll
        for (int m = 0; m < 4; ++m)
            af[m] = *(const bf16x8*)&As[(wm + m * 16 + l15) * LDT + l4 * 8];
#pragma unroll
        for (int n = 0; n < 4; ++n)
            bfr[n] = *(const bf16x8*)&Bs[(wn + n * 16 + l15) * LDT + l4 * 8];
#pragma unroll
        for (int m = 0; m < 4; ++m)
#pragma unroll
            for (int n = 0; n < 4; ++n)
                acc[m][n] = __builtin_amdgcn_mfma_f32_16x16x32_bf16(af[m], bfr[n], acc[m][n], 0, 0, 0);
    }

    // Epilogue: D row=(lane>>4)*4+j, col=lane&15
#pragma unroll
    for (int m = 0; m < 4; ++m) {
        int frow = row0 + wm + m * 16 + l4 * 4;
#pragma unroll
        for (int n = 0; n < 4; ++n) {
            int fcol = bn0 + wn + n * 16 + l15;
            float bb = bias[fcol];
#pragma unroll
            for (int j = 0; j < 4; ++j) {
                int r = frow + j;
                if (r < M) {
                    float v = acc[m][n][j] + bb;
                    if constexpr (RESID) v += resid[(size_t)r * 256 + fcol];
                    if constexpr (PADMAP) {
                        int pr = pad_row_idx(r);
                        ((bf16*)outv)[(size_t)pr * 256 + fcol] = __float2bfloat16(v);
                    } else if constexpr (OUT_BF16) {
                        ((bf16*)outv)[(size_t)r * ldo + fcol] = __float2bfloat16(v);
                    } else {
                        ((float*)outv)[(size_t)r * ldo + fcol] = v;
                    }
                }
            }
        }
    }
}

// ---------------------------------------------------------------------------
// MSDA sampling v4: 2 queries per wave, 8 queries per 256-thread block.
// lane = qs*32 + h*4 + s ; lane owns 8 channels (uint4 bf16 gathers).
// vproj is zero-padded per level -> no bounds masking, just clamp.
// offawl rows are bf16 [off(256)|awl(128)], stride 384. msda (bf16) written
// over the off portion of the same rows (block-exclusive rows -> safe).
// ---------------------------------------------------------------------------
__device__ inline f32x2 bfpair(unsigned u) {
    f32x2 r;
    r.x = __uint_as_float(u << 16);
    r.y = __uint_as_float(u & 0xffff0000u);
    return r;
}

__global__ __launch_bounds__(256) void msda_sample4(
    const bf16* __restrict__ vproj,      // padded layout, [2*PTOT][256]
    const bf16* __restrict__ offawl,     // [MROWS][384]
    const float* __restrict__ refp,
    bf16* __restrict__ msda_out)         // aliases offawl rows (stride 384)
{
    __shared__ uint2 sOA[8][128];        // 8 rows x 1024B (payload 768B)
    __shared__ float sRef[8][8];

    const int tid = threadIdx.x;
    const int q0 = blockIdx.x * 8;

    // stage 8 offawl rows (768B each) + 8 refp rows
#pragma unroll
    for (int k = 0; k < 4; ++k) {
        int idx = tid + k * 256;         // 0..1023 over LDS slots
        int row = idx >> 7, e = idx & 127;
        if (e < 96) {
            int grow = min(q0 + row, MROWS - 1);
            sOA[row][e] = *((const uint2*)(offawl + (size_t)grow * 384) + e);
        }
    }
    if (tid < 64) {
        int row = tid >> 3, er = tid & 7;
        int grow = min(q0 + row, MROWS - 1);
        sRef[row][er] = refp[(size_t)grow * 8 + er];
    }
    __syncthreads();

    const int w = tid >> 6;
    const int lane = tid & 63;
    const int qs = lane >> 5;
    const int h = (lane >> 2) & 7;
    const int s = lane & 3;
    const int qrow = w * 2 + qs;
    int q = q0 + qrow;
    const bool alive = q < MROWS;
    if (!alive) q = MROWS - 1;
    const int b = (q >= NQ) ? 1 : 0;

    // per-(q,h) sampling offsets: 16 packed bf16-pairs
    const char* rowp = (const char*)&sOA[qrow][0];
    unsigned off16[16];
    {
        uint4 o0 = *(const uint4*)(rowp + h * 64);
        uint4 o1 = *(const uint4*)(rowp + h * 64 + 16);
        uint4 o2 = *(const uint4*)(rowp + h * 64 + 32);
        uint4 o3 = *(const uint4*)(rowp + h * 64 + 48);
        off16[0]=o0.x; off16[1]=o0.y; off16[2]=o0.z; off16[3]=o0.w;
        off16[4]=o1.x; off16[5]=o1.y; off16[6]=o1.z; off16[7]=o1.w;
        off16[8]=o2.x; off16[9]=o2.y; off16[10]=o2.z; off16[11]=o2.w;
        off16[12]=o3.x; off16[13]=o3.y; off16[14]=o3.z; off16[15]=o3.w;
    }

    // softmax over this head's 16 logits
    float aw[16];
    {
        uint4 g0 = *(const uint4*)(rowp + 512 + h * 32);
        uint4 g1 = *(const uint4*)(rowp + 512 + h * 32 + 16);
        unsigned gu[8] = {g0.x,g0.y,g0.z,g0.w,g1.x,g1.y,g1.z,g1.w};
        float lg[16];
#pragma unroll
        for (int i = 0; i < 8; ++i) {
            f32x2 p = bfpair(gu[i]);
            lg[2*i] = p.x; lg[2*i+1] = p.y;
        }
        float mx = lg[0];
#pragma unroll
        for (int i = 1; i < 16; ++i) mx = fmaxf(mx, lg[i]);
        float ssum = 0.f;
#pragma unroll
        for (int i = 0; i < 16; ++i) { aw[i] = __expf(lg[i] - mx); ssum += aw[i]; }
        float inv = 1.f / ssum;
#pragma unroll
        for (int i = 0; i < 16; ++i) aw[i] *= inv;
    }

    f32x2 a0 = {0.f,0.f}, a1 = {0.f,0.f}, a2 = {0.f,0.f}, a3 = {0.f,0.f};

#pragma unroll
    for (int l = 0; l < 4; ++l) {
        const int W = LW[l], H = LH[l], Wp = PLW[l];
        // padded-coordinate base: x_pad = ref.x*W - 0.5 + off + 1
        const float xb = sRef[qrow][l * 2 + 0] * (float)W + 0.5f;
        const float yb = sRef[qrow][l * 2 + 1] * (float)LH[l] + 0.5f;
        const bf16* vl = vproj + ((size_t)(b * PTOT + PLSTART[l])) * 256 + h * 32 + s * 8;
#pragma unroll
        for (int p = 0; p < 4; ++p) {
            const int t = l * 4 + p;
            f32x2 o2 = bfpair(off16[t]);
            float x = xb + o2.x;
            float y = yb + o2.y;
            x = fminf(fmaxf(x, 0.f), (float)(W + 1));
            y = fminf(fmaxf(y, 0.f), (float)(H + 1));
            float x0f = floorf(x), y0f = floorf(y);
            float lx = x - x0f, ly = y - y0f;
            int x0 = (int)x0f, y0 = (int)y0f;
            const bf16* r0 = vl + (size_t)((y0 * Wp + x0) * 256);
            const bf16* r1 = r0 + Wp * 256;
            uint4 c00 = *(const uint4*)r0;
            uint4 c01 = *(const uint4*)(r0 + 256);
            uint4 c10 = *(const uint4*)r1;
            uint4 c11 = *(const uint4*)(r1 + 256);
            float aww = aw[t];
            float wx1 = lx, wx0 = 1.f - lx;
            float wy0 = (1.f - ly) * aww, wy1 = ly * aww;
            float w00 = wx0 * wy0, w01 = wx1 * wy0;
            float w10 = wx0 * wy1, w11 = wx1 * wy1;

#define CORNER(c, wt) { f32x2 wv = {wt, wt};            \
            a0 += bfpair(c.x) * wv; a1 += bfpair(c.y) * wv; \
            a2 += bfpair(c.z) * wv; a3 += bfpair(c.w) * wv; }
            CORNER(c00, w00) CORNER(c01, w01) CORNER(c10, w10) CORNER(c11, w11)
#undef CORNER
        }
    }

    if (alive) {
        bf16 o[8];
        o[0] = __float2bfloat16(a0.x); o[1] = __float2bfloat16(a0.y);
        o[2] = __float2bfloat16(a1.x); o[3] = __float2bfloat16(a1.y);
        o[4] = __float2bfloat16(a2.x); o[5] = __float2bfloat16(a2.y);
        o[6] = __float2bfloat16(a3.x); o[7] = __float2bfloat16(a3.y);
        *(uint4*)(msda_out + (size_t)q * 384 + h * 32 + s * 8) = *(const uint4*)o;
    }
}

// ---------------------------------------------------------------------------
extern "C" void kernel_launch(void* const* d_in, const int* in_sizes, int n_in,
                              void* d_out, int out_size, void* d_ws, size_t ws_size,
                              hipStream_t stream) {
    const float* query = (const float*)d_in[0];
    const float* value = (const float*)d_in[1];
    const float* refp  = (const float*)d_in[2];
    const float* W_so  = (const float*)d_in[3];
    const float* b_so  = (const float*)d_in[4];
    const float* W_aw  = (const float*)d_in[5];
    const float* b_aw  = (const float*)d_in[6];
    const float* W_vp  = (const float*)d_in[7];
    const float* b_vp  = (const float*)d_in[8];
    const float* W_op  = (const float*)d_in[9];
    const float* b_op  = (const float*)d_in[10];
    float* out = (float*)d_out;

    // Workspace:
    //   offawl : bf16 MROWS*384 (34.1 MB) [off|awl]; msda bf16 aliased over rows
    //   vproj  : bf16 2*PTOT*256 (24.3 MB) zero-padded level layout
    //   weights: Wt_cat 384*256, Wt_vp/Wt_op 256*256 bf16, bcat 384 f32
    bf16* d_offawl = (bf16*)d_ws;
    bf16* d_vproj  = d_offawl + (size_t)MROWS * 384;
    bf16* d_wtcat  = d_vproj + (size_t)2 * PTOT * 256;
    bf16* d_wtvp   = d_wtcat + 384 * 256;
    bf16* d_wtop   = d_wtvp + 256 * 256;
    float* d_bcat  = (float*)(d_wtop + 256 * 256);

    const int gx = (MROWS + BM - 1) / BM;   // 348

    prep_weights<<<384, 256, 0, stream>>>(W_vp, W_so, W_aw, W_op, b_so, b_aw,
                                          d_wtvp, d_wtcat, d_wtop, d_bcat);
    // zero padded vproj (borders must be 0)
    hipMemsetAsync(d_vproj, 0, (size_t)2 * PTOT * 256 * sizeof(bf16), stream);
    // offawl (bf16) = query @ [W_so|W_aw] + bcat
    gemm_mfma<false, true, false, false><<<dim3(gx, 3), 256, 0, stream>>>(
        query, 256, d_wtcat, d_bcat, nullptr, d_offawl, 384, MROWS);
    // vproj (bf16, padded scatter) = value @ W_vp + b_vp
    gemm_mfma<false, true, false, true><<<dim3(gx, 2), 256, 0, stream>>>(
        value, 256, d_wtvp, b_vp, nullptr, d_vproj, 256, MROWS);
    // sampling
    msda_sample4<<<(MROWS + 7) / 8, 256, 0, stream>>>(
        d_vproj, d_offawl, refp, d_offawl);
    // out = msda @ W_op + b_op + query
    gemm_mfma<true, false, true, false><<<dim3(gx, 2), 256, 0, stream>>>(
        d_offawl, 384, d_wtop, b_op, query, out, 256, MROWS);
}